// Round 8
// baseline (826.221 us; speedup 1.0000x reference)
//
#include <hip/hip_runtime.h>

// LSTM feedback net: B=16384, T=48 warmup, F=4, UNITS=256, 24 AR steps.
// R8: (1) GEMM on mfma_f32_32x32x16_bf16 (8.07 vs 2x4.85 cyc/CU for same
// FLOPs, half the MFMA instructions; A-frag per (gate,kt) shared across both
// 32-row batch tiles -> ~40 VGPRs freed). (2) freed regs: c in registers,
// 3-deep W/h rings with peeled tail under #pragma unroll 1 (anti-spill).
// (3) transcendentals 10->8 per element: i*g = (1-eg)/((1+ei)(1+eg)),
// o*tanh(cn) = (1-ec)/((1+eo)(1+ec)) -- one rcp each.
// Layouts (32x32x16): A[row=l&31][k=(l>>5)*8+j], B[k=(l>>5)*8+j][col=l&31],
// D col=lane&31, row=(reg&3)+8*(reg>>2)+4*(lane>>5)  [m74/m101].

typedef unsigned short u16;
typedef __attribute__((ext_vector_type(8))) short bf16x8;
typedef __attribute__((ext_vector_type(16))) float f32x16;

#define PITCH 296    // hext row pitch, elems (592 B/row)
#define HB 18944     // elems per h buffer (64*296)
#define WARM 48
#define STEPS 71     // 48 warmup + 23 AR cell steps
#define LOG2E  1.442695041f
#define LOG2E2 2.885390082f

__device__ __forceinline__ u16 f2bf(float f) {
    unsigned u = __float_as_uint(f);
    u += 0x7FFFu + ((u >> 16) & 1u);   // round-to-nearest-even
    return (u16)(u >> 16);
}

// LDS-only barrier: drain LDS ops, NOT vmcnt -> global loads stay in flight.
__device__ __forceinline__ void sync_lds() {
    asm volatile("s_waitcnt lgkmcnt(0)\n\ts_barrier" ::: "memory");
}

// ---- prep: pack W' (K=288 x N=1024, z-cols [i|f|g|o]x256) as 32x32x16
// A-fragments. Frag (kt,g,w): lane l, j=0..7 holds
//   W'[k = kt*16 + (l>>5)*8 + j][n = 256g + 32w + (l&31)]
// K rows: 0..255 Wh, 256..259 Wx, 260 bias, else 0. Cols pre-scaled by
// log2e (i,f,o) / 2*log2e (g). Wd packed likewise (18 frags, f = l&31 < 4).
__global__ void prep_weights(const float* __restrict__ Wx,
                             const float* __restrict__ Wh,
                             const float* __restrict__ b,
                             const float* __restrict__ Wd,
                             const float* __restrict__ bd,
                             u16* __restrict__ whext,
                             u16* __restrict__ wdp) {
    int idx = blockIdx.x * 256 + threadIdx.x;   // one thread per 16B chunk
    if (idx < 36864) {                          // 18 kt * 4 g * 8 w * 64 lanes
        int lane = idx & 63;
        int frag = idx >> 6;
        int wv = frag & 7;
        int g = (frag >> 3) & 3;
        int kt = frag >> 5;
        int k0 = kt * 16 + (lane >> 5) * 8;
        int n = 256 * g + 32 * wv + (lane & 31);
        float sc = (g == 2) ? LOG2E2 : LOG2E;
        u16 v[8];
#pragma unroll
        for (int j = 0; j < 8; ++j) {
            int k = k0 + j;
            float f = 0.0f;
            if (k < 256) f = Wh[k * 1024 + n];
            else if (k < 260) f = Wx[(k - 256) * 1024 + n];
            else if (k == 260) f = b[n];
            v[j] = f2bf(f * sc);
        }
        ushort4* dst = (ushort4*)(whext + (size_t)idx * 8);
        dst[0] = make_ushort4(v[0], v[1], v[2], v[3]);
        dst[1] = make_ushort4(v[4], v[5], v[6], v[7]);
    } else if (idx < 36864 + 1152) {            // Wd: 18 frags x 64 lanes
        int id2 = idx - 36864;
        int lane = id2 & 63;
        int kt = id2 >> 6;
        int k0 = kt * 16 + (lane >> 5) * 8;
        int f_ = lane & 31;
        u16 v[8];
#pragma unroll
        for (int j = 0; j < 8; ++j) {
            int k = k0 + j;
            float f = 0.0f;
            if (f_ < 4) {
                if (k < 256) f = Wd[k * 4 + f_];
                else if (k == 260) f = bd[f_];
            }
            v[j] = f2bf(f);
        }
        ushort4* dst = (ushort4*)(wdp + (size_t)id2 * 8);
        dst[0] = make_ushort4(v[0], v[1], v[2], v[3]);
        dst[1] = make_ushort4(v[4], v[5], v[6], v[7]);
    }
}

#define WLOAD(DST, KTV) do {                                                  \
    const char* _wpk = wp + (size_t)(KTV) * 32768;                            \
    _Pragma("unroll") for (int g = 0; g < 4; ++g)                             \
        DST[g] = *(const bf16x8*)(_wpk + voff[g]);                            \
} while (0)

#define HLOAD(DST, KTV) do {                                                  \
    DST[0] = *(const bf16x8*)&hr[hrow0 + (KTV) * 16];                         \
    DST[1] = *(const bf16x8*)&hr[hrow1 + (KTV) * 16];                         \
} while (0)

#define MT(WA, HBX)                                                           \
    _Pragma("unroll") for (int m = 0; m < 2; ++m)                             \
    _Pragma("unroll") for (int g = 0; g < 4; ++g)                             \
        acc[m][g] = __builtin_amdgcn_mfma_f32_32x32x16_bf16(                  \
            WA[g], HBX[m], acc[m][g], 0, 0, 0);

__global__ __launch_bounds__(512, 2) void lstm_main(
    const float* __restrict__ x, const u16* __restrict__ whext,
    const u16* __restrict__ wdp, float* __restrict__ out) {
    __shared__ __align__(16) u16 hbuf[2 * HB];   // h double buffer only

    const int tid = threadIdx.x;
    const int w = tid >> 6;        // wave 0..7 -> units [32w, 32w+32)
    const int l = tid & 63;
    const int l31 = l & 31;
    const int lh = l >> 5;
    const long long rowBase = (long long)blockIdx.x * 64;

    {   // zero both h buffers (incl. K-pad cols 261..287)
        int4 z = make_int4(0, 0, 0, 0);
        for (int i = tid; i < 4736; i += 512) ((int4*)hbuf)[i] = z;
    }
    sync_lds();
    if (tid < 64) {
        hbuf[tid * PITCH + 260] = (u16)0x3F80;        // bias-1 col, buffer 0
        hbuf[HB + tid * PITCH + 260] = (u16)0x3F80;   // and buffer 1
        const float4 xv = *(const float4*)(x + (rowBase + tid) * 192);
        u16* p = &hbuf[tid * PITCH + 256];             // x_0 -> buffer 0
        p[0] = f2bf(xv.x); p[1] = f2bf(xv.y); p[2] = f2bf(xv.z); p[3] = f2bf(xv.w);
    }

    const char* __restrict__ wp = (const char*)whext;
    const char* __restrict__ dp = (const char*)wdp;
    int voff[4];   // per-lane byte offset of frag (kt=0, g, w)
#pragma unroll
    for (int g = 0; g < 4; ++g) voff[g] = ((g * 8 + w) * 64 + l) * 16;
    const int hrow0 = l31 * PITCH + lh * 8;          // B-frag row, m=0 (elems)
    const int hrow1 = (32 + l31) * PITCH + lh * 8;   // m=1

    f32x16 c[2] = {};      // cell state: m -> batch 32m+l31; reg r -> unit
                           // 32w + (r&3) + 8*(r>>2) + 4*lh
    bf16x8 awA[4], awB[4], awC[4];
    WLOAD(awA, 0);         // pre-barrier; in flight across sync_lds
    WLOAD(awB, 1);

    for (int step = 0; step < STEPS; ++step) {
        const u16* hr = hbuf + (step & 1) * HB;      // read buffer
        u16* hw = hbuf + ((step & 1) ^ 1) * HB;      // write buffer
        sync_lds();   // hr ready; prior reads of hw done

        f32x16 acc[2][4] = {};   // [batch-tile m][gate]
        bf16x8 hbA[2], hbB[2], hbC[2];
        HLOAD(hbA, 0);
        HLOAD(hbB, 1);

#pragma unroll 1
        for (int t = 0; t < 15; t += 3) {
            WLOAD(awC, t + 2); HLOAD(hbC, t + 2);
            MT(awA, hbA);                    // tile t
            WLOAD(awA, t + 3); HLOAD(hbA, t + 3);
            MT(awB, hbB);                    // tile t+1
            WLOAD(awB, t + 4); HLOAD(hbB, t + 4);
            MT(awC, hbC);                    // tile t+2
        }
        WLOAD(awC, 17); HLOAD(hbC, 17);
        MT(awA, hbA);                        // tile 15
        WLOAD(awA, 0);                       // next-step tile 0 (flies over gates+barrier)
        MT(awB, hbB);                        // tile 16
        WLOAD(awB, 1);                       // next-step tile 1
        MT(awC, hbC);                        // tile 17

        // gates; weights pre-scaled so e = 2^-z' forms. 8 transcendentals/elem:
        // i*g = (1-eg)/((1+ei)(1+eg)), cn = c*rcp(1+ef) + i*g,
        // h = o*tanh(cn) = (1-ec)/((1+eo)(1+ec)).
#pragma unroll
        for (int m = 0; m < 2; ++m) {
            const int hwrow = (32 * m + l31) * PITCH + 32 * w + 4 * lh;
#pragma unroll
            for (int q = 0; q < 4; ++q) {
                u16 hh[4];
#pragma unroll
                for (int rr = 0; rr < 4; ++rr) {
                    const int r = q * 4 + rr;
                    float ei = __builtin_amdgcn_exp2f(-acc[m][0][r]);
                    float ef = __builtin_amdgcn_exp2f(-acc[m][1][r]);
                    float eg = __builtin_amdgcn_exp2f(-acc[m][2][r]);
                    float eo = __builtin_amdgcn_exp2f(-acc[m][3][r]);
                    float fv  = __builtin_amdgcn_rcpf(1.0f + ef);
                    float rig = __builtin_amdgcn_rcpf((1.0f + ei) * (1.0f + eg));
                    float cn  = c[m][r] * fv + (1.0f - eg) * rig;
                    c[m][r] = cn;
                    float ec = __builtin_amdgcn_exp2f(-LOG2E2 * cn);
                    float roc = __builtin_amdgcn_rcpf((1.0f + eo) * (1.0f + ec));
                    hh[rr] = f2bf((1.0f - ec) * roc);
                }
                *(ushort4*)&hw[hwrow + 8 * q] = make_ushort4(hh[0], hh[1], hh[2], hh[3]);
            }
        }

        if (step < WARM - 1) {
            if (w == 0) {   // x_{step+1} -> write buffer (read next step)
                const float4 xv = *(const float4*)(x + (rowBase + l) * 192 + (step + 1) * 4);
                u16* p = &hw[l * PITCH + 256];
                p[0] = f2bf(xv.x); p[1] = f2bf(xv.y); p[2] = f2bf(xv.z); p[3] = f2bf(xv.w);
            }
        } else {
            sync_lds();        // h_new in hw visible for pred GEMM
            if (w < 2) {       // pred^T = Wd'^T @ h_new^T ; wave w -> batch-tile w
                f32x16 pacc = {};
                const int prow = (32 * w + l31) * PITCH + lh * 8;
#pragma unroll
                for (int kt = 0; kt < 18; ++kt) {
                    bf16x8 hbp = *(const bf16x8*)&hw[prow + kt * 16];
                    bf16x8 wap = *(const bf16x8*)(dp + ((size_t)kt * 64 + l) * 16);
                    pacc = __builtin_amdgcn_mfma_f32_32x32x16_bf16(wap, hbp, pacc, 0, 0, 0);
                }
                if (lh == 0) {   // rows 0..3 (= features) live in regs 0..3 of lanes 0..31
                    int s = step - (WARM - 1);
                    int batch = 32 * w + l31;
                    *(float4*)&out[((rowBase + batch) * 24 + s) * 4] =
                        make_float4(pacc[0], pacc[1], pacc[2], pacc[3]);
                    *(ushort4*)&hw[batch * PITCH + 256] =   // feed back as next x_t
                        make_ushort4(f2bf(pacc[0]), f2bf(pacc[1]), f2bf(pacc[2]), f2bf(pacc[3]));
                }
            }
        }
    }
}

extern "C" void kernel_launch(void* const* d_in, const int* in_sizes, int n_in,
                              void* d_out, int out_size, void* d_ws, size_t ws_size,
                              hipStream_t stream) {
    const float* x  = (const float*)d_in[0];   // [16384,48,4]
    const float* Wx = (const float*)d_in[1];   // [4,1024]
    const float* Wh = (const float*)d_in[2];   // [256,1024]
    const float* b  = (const float*)d_in[3];   // [1024]
    const float* Wd = (const float*)d_in[4];   // [256,4]
    const float* bd = (const float*)d_in[5];   // [4]
    float* out = (float*)d_out;                // [16384,24,4] fp32

    u16* whext = (u16*)d_ws;                        // 589824 B
    u16* wdp = (u16*)((char*)d_ws + 589824);        // 18432 B

    prep_weights<<<(36864 + 1152 + 255) / 256, 256, 0, stream>>>(Wx, Wh, b, Wd, bd, whext, wdp);
    lstm_main<<<256, 512, 0, stream>>>(x, whext, wdp, out);
}